// Round 12
// baseline (231.243 us; speedup 1.0000x reference)
//
#include <hip/hip_runtime.h>
#include <cstdint>
#include <cstddef>

#define T_TOK 32768
#define DM 768
#define EDIM 192
#define NEXP 8

typedef unsigned short u16;
typedef short bf16x8 __attribute__((ext_vector_type(8)));
typedef float f32x4 __attribute__((ext_vector_type(4)));
typedef u16 u16x8 __attribute__((ext_vector_type(8)));

__device__ __forceinline__ u16 f2bf(float f) {
  unsigned u = __float_as_uint(f);
  return (u16)((u + 0x7FFFu + ((u >> 16) & 1u)) >> 16);  // RNE
}
__device__ __forceinline__ float bf2f(u16 u) {
  return __uint_as_float(((unsigned)u) << 16);
}

// async global->LDS, 16B per lane. LDS dest must be wave-uniform base + lane*16.
__device__ __forceinline__ void gld16(const void* g, void* l) {
  __builtin_amdgcn_global_load_lds(
      (const __attribute__((address_space(1))) unsigned int*)g,
      (__attribute__((address_space(3))) unsigned int*)l,
      16, 0, 0);
}

// Read one MFMA fragment (8 bf16) from a swizzled LDS tile with 128-byte rows.
// Swizzle: phys_byte = row*128 + (kb ^ ((row&7)<<4))
__device__ __forceinline__ bf16x8 frag_ld(const u16* lds, int row, int kb) {
  int ph = row * 128 + (kb ^ ((row & 7) << 4));
  return *(const bf16x8*)((const char*)lds + ph);
}

// ---------------------------------------------------------------------------
// Fused: tokenize+router (blocks 0..1023) and weight transpose (blocks
// 1024..1887). Independent tasks overlapped in one dispatch.
// ---------------------------------------------------------------------------
__global__ __launch_bounds__(256) void k_tokprep(
    const float* __restrict__ x, const float* __restrict__ Wr,
    const float* __restrict__ W1, const float* __restrict__ W3,
    const float* __restrict__ W2,
    u16* __restrict__ tokbf, int* __restrict__ cnt,
    int* __restrict__ toklist, float* __restrict__ gatelist,
    u16* __restrict__ W1T, u16* __restrict__ W3T, u16* __restrict__ W2T)
{
  __shared__ __align__(16) char smraw[34304];
  const int tid = threadIdx.x;
  const int bx = blockIdx.x;

  if (bx >= 1024) {
    // ---- prep path: transpose + fp32->bf16 ----
    float (*td)[68] = (float(*)[68])smraw;   // [64][68]
    const int pid = bx - 1024;               // 0..863
    const int mat = pid / 288;
    const int rem = pid - mat * 288;
    const int e = rem / 36;
    const int tile = rem - e * 36;
    int R, C, r0, c0;
    if (mat < 2) { R = DM; C = EDIM; r0 = (tile / 3) * 64; c0 = (tile % 3) * 64; }
    else         { R = EDIM; C = DM; r0 = (tile / 12) * 64; c0 = (tile % 12) * 64; }
    const float* in = (mat == 0 ? W1 : mat == 1 ? W3 : W2) + (size_t)e * R * C;
    u16* out = (mat == 0 ? W1T : mat == 1 ? W3T : W2T) + (size_t)e * R * C;
    {
      int rl = tid >> 2, cs = (tid & 3) * 16;
      const float* s = in + (size_t)(r0 + rl) * C + c0 + cs;
      #pragma unroll
      for (int i = 0; i < 16; i += 4) *(float4*)&td[rl][cs + i] = *(const float4*)(s + i);
    }
    __syncthreads();
    {
      int cl = tid >> 2, rs = (tid & 3) * 16;
      u16* d = out + (size_t)(c0 + cl) * R + r0 + rs;
      u16x8 o0, o1;
      #pragma unroll
      for (int i = 0; i < 8; ++i) {
        o0[i] = f2bf(td[rs + i][cl]);
        o1[i] = f2bf(td[rs + 8 + i][cl]);
      }
      *(u16x8*)d = o0;
      *(u16x8*)(d + 8) = o1;
    }
    return;
  }

  // ---- router path ----
  float (*WrL)[772]    = (float(*)[772])smraw;                 // 24704 B
  float (*xL)[33]      = (float(*)[33])(smraw + 24704);        //  8448 B
  float (*logitsL)[8]  = (float(*)[8])(smraw + 33152);         //  1024 B
  int* cnt8            = (int*)(smraw + 34176);                //    32 B
  int* baseL           = (int*)(smraw + 34208);                //    32 B

  const int t0 = bx * 32;
  const int b = t0 >> 10;
  const int h = (t0 >> 5) & 31;
  const float* xb = x + (size_t)b * (DM * 1024) + h * 32;

  for (int i = tid; i < 1536; i += 256) {
    int r = i / 192;
    int c = (i - r * 192) * 4;
    *(float4*)&WrL[r][c] = ((const float4*)Wr)[i];
  }

  const int rt = tid >> 3;
  const int re = tid & 7;
  float lacc = 0.f;

  for (int cb = 0; cb < 12; ++cb) {
    const int c0 = cb * 64;
    __syncthreads();
    #pragma unroll
    for (int it = 0; it < 2; ++it) {
      int idx = it * 256 + tid;
      int r = idx >> 3, cc = (idx & 7) * 4;
      float4 v = *(const float4*)(xb + (size_t)(c0 + r) * 1024 + cc);
      xL[r][cc] = v.x; xL[r][cc + 1] = v.y; xL[r][cc + 2] = v.z; xL[r][cc + 3] = v.w;
    }
    __syncthreads();
    {
      const float* wr = &WrL[re][c0];
      #pragma unroll
      for (int c = 0; c < 64; ++c) lacc = fmaf(xL[c][rt], wr[c], lacc);
    }
    {
      u16x8 o;
      #pragma unroll
      for (int i = 0; i < 8; ++i) o[i] = f2bf(xL[re * 8 + i][rt]);
      *(u16x8*)(tokbf + (size_t)(t0 + rt) * DM + c0 + re * 8) = o;
    }
  }

  logitsL[rt][re] = lacc;
  if (tid < 8) cnt8[tid] = 0;
  __syncthreads();

  int e0 = -1, e1 = -1, lp0 = 0, lp1 = 0;
  float g0 = 0.f, g1 = 0.f;
  if (tid < 32) {
    float v0 = -1e30f, v1 = -1e30f;
    #pragma unroll
    for (int e = 0; e < 8; ++e) { float v = logitsL[tid][e]; if (v > v0) { v0 = v; e0 = e; } }
    #pragma unroll
    for (int e = 0; e < 8; ++e) {
      if (e == e0) continue;
      float v = logitsL[tid][e]; if (v > v1) { v1 = v; e1 = e; }
    }
    float w = expf(v1 - v0);
    g0 = 1.f / (1.f + w);
    g1 = w / (1.f + w);
    lp0 = atomicAdd(&cnt8[e0], 1);
    lp1 = atomicAdd(&cnt8[e1], 1);
  }
  __syncthreads();
  if (tid < 8) baseL[tid] = atomicAdd(&cnt[tid], cnt8[tid]);
  __syncthreads();
  if (tid < 32) {
    int tg = t0 + tid;
    int p0 = baseL[e0] + lp0;
    int p1 = baseL[e1] + lp1;
    toklist[e0 * T_TOK + p0] = tg;
    gatelist[e0 * T_TOK + p0] = g0;
    toklist[e1 * T_TOK + p1] = tg | (1 << 16);
    gatelist[e1 * T_TOK + p1] = g1;
  }
}

// ---------------------------------------------------------------------------
// Stage 1: h = silu(tok @ W1) * (tok @ W3). Tile 128x64, BK=64, 4 waves,
// T3-minimum double-buffered schedule: STAGE(next-buf) issued BEFORE
// compute(cur), ONE implicit-vmcnt(0) barrier per K-step (12 barriers vs 24).
// LDS 66KB -> 2 blocks/CU. Grid (256, 3, 8).
// ---------------------------------------------------------------------------
__global__ __launch_bounds__(256) void k_ffn1(
    const u16* __restrict__ tokbf, const u16* __restrict__ W1T,
    const u16* __restrict__ W3T, const int* __restrict__ cnt,
    const int* __restrict__ toklist, u16* __restrict__ hbuf)
{
  __shared__ __align__(16) u16 As[2][128 * 64];
  __shared__ __align__(16) u16 B1s[2][64 * 64];
  __shared__ __align__(16) u16 B3s[2][64 * 64];
  __shared__ int rowbaseL[128];
  const int e = blockIdx.z;
  const int count = cnt[e];
  const int start = blockIdx.x * 128;
  if (start >= count) return;
  const int n0 = blockIdx.y * 64;
  const int rows = min(128, count - start);
  const int tid = threadIdx.x;

  int offe = 0;
  #pragma unroll
  for (int i = 0; i < NEXP; ++i) offe += (i < e) ? cnt[i] : 0;

  if (tid < 128) {
    int r = (tid < rows) ? tid : 0;
    rowbaseL[tid] = (toklist[e * T_TOK + start + r] & 0xFFFF) * DM;
  }
  __syncthreads();

  // kc-invariant staging addresses (swizzle applied on the global source)
  const int lrow = tid >> 3;                                   // 0..31
  const int swq = (((tid & 7) * 16) ^ ((lrow & 7) << 4)) >> 1; // u16 units
  const u16 *srcA[4], *srcB1[2], *srcB3[2];
  #pragma unroll
  for (int it = 0; it < 4; ++it)
    srcA[it] = tokbf + rowbaseL[it * 32 + lrow] + swq;
  #pragma unroll
  for (int it = 0; it < 2; ++it) {
    size_t wb = (size_t)(e * EDIM + n0 + it * 32 + lrow) * DM + swq;
    srcB1[it] = W1T + wb;
    srcB3[it] = W3T + wb;
  }
  const int dOff = tid * 16;

  auto stage = [&](int bb, int kc) {
    const int ko = kc * 64;
    #pragma unroll
    for (int it = 0; it < 4; ++it)
      gld16(srcA[it] + ko, (char*)As[bb] + it * 4096 + dOff);
    #pragma unroll
    for (int it = 0; it < 2; ++it) {
      gld16(srcB1[it] + ko, (char*)B1s[bb] + it * 4096 + dOff);
      gld16(srcB3[it] + ko, (char*)B3s[bb] + it * 4096 + dOff);
    }
  };

  const int w = tid >> 6, l = tid & 63;
  const int wm = (w >> 1) * 64, wn = (w & 1) * 32;
  const int lr = l & 15;
  const int lk = (l >> 4) * 16;

  f32x4 acc1[4][2], acc3[4][2];
  #pragma unroll
  for (int i = 0; i < 4; ++i)
    #pragma unroll
    for (int j = 0; j < 2; ++j) {
      acc1[i][j] = (f32x4){0.f, 0.f, 0.f, 0.f};
      acc3[i][j] = (f32x4){0.f, 0.f, 0.f, 0.f};
    }

  stage(0, 0);
  __syncthreads();   // implicit vmcnt(0) before barrier: buf0 ready

  for (int kc = 0; kc < 12; ++kc) {
    const int cur = kc & 1;
    if (kc < 11) stage(cur ^ 1, kc + 1);   // overlap next-tile loads with compute
    #pragma unroll
    for (int kk = 0; kk < 2; ++kk) {
      const int kb = kk * 64 + lk;
      bf16x8 af[4], b1[2], b3[2];
      #pragma unroll
      for (int mf = 0; mf < 4; ++mf) af[mf] = frag_ld(As[cur], wm + mf * 16 + lr, kb);
      #pragma unroll
      for (int nf = 0; nf < 2; ++nf) {
        b1[nf] = frag_ld(B1s[cur], wn + nf * 16 + lr, kb);
        b3[nf] = frag_ld(B3s[cur], wn + nf * 16 + lr, kb);
      }
      #pragma unroll
      for (int mf = 0; mf < 4; ++mf)
        #pragma unroll
        for (int nf = 0; nf < 2; ++nf) {
          acc1[mf][nf] = __builtin_amdgcn_mfma_f32_16x16x32_bf16(af[mf], b1[nf], acc1[mf][nf], 0, 0, 0);
          acc3[mf][nf] = __builtin_amdgcn_mfma_f32_16x16x32_bf16(af[mf], b3[nf], acc3[mf][nf], 0, 0, 0);
        }
    }
    __syncthreads();  // one barrier/K-step: drains next-tile loads (vmcnt0)
                      // + guards cur-buf reads before kc+1 restages it
  }

  const int rq = (l >> 4) * 4;
  const int abase = offe + start;
  #pragma unroll
  for (int mf = 0; mf < 4; ++mf)
    #pragma unroll
    for (int nf = 0; nf < 2; ++nf)
      #pragma unroll
      for (int r = 0; r < 4; ++r) {
        int m = wm + mf * 16 + rq + r;
        if (m < rows) {
          float a = acc1[mf][nf][r];
          float hv = (a / (1.f + expf(-a))) * acc3[mf][nf][r];
          hbuf[(size_t)(abase + m) * EDIM + (n0 + wn + nf * 16 + lr)] = f2bf(hv);
        }
      }
}

// ---------------------------------------------------------------------------
// Stage 2: ypart[k][t][:] = gate * (h @ W2[e]). Tile 128x128, K=192, 4 waves,
// single-buffered 33KB (R8-proven). Grid (256, 6, 8).
// ---------------------------------------------------------------------------
__global__ __launch_bounds__(256) void k_ffn2(
    const u16* __restrict__ hbuf, const u16* __restrict__ W2T,
    const int* __restrict__ cnt, const int* __restrict__ toklist,
    const float* __restrict__ gatelist, u16* __restrict__ ypart)
{
  __shared__ __align__(16) u16 As[128 * 64];
  __shared__ __align__(16) u16 Bs[128 * 64];
  __shared__ int dstL[128];
  __shared__ float gL[128];
  const int e = blockIdx.z;
  const int count = cnt[e];
  const int start = blockIdx.x * 128;
  if (start >= count) return;
  const int n0 = blockIdx.y * 128;
  const int rows = min(128, count - start);
  const int tid = threadIdx.x;

  int offe = 0;
  #pragma unroll
  for (int i = 0; i < NEXP; ++i) offe += (i < e) ? cnt[i] : 0;
  const int abase = offe + start;

  if (tid < 128) {
    int r = (tid < rows) ? tid : 0;
    int entry = toklist[e * T_TOK + start + r];
    int t = entry & 0xFFFF, k = entry >> 16;
    dstL[tid] = (k * T_TOK + t) * DM;
    gL[tid] = gatelist[e * T_TOK + start + r];
  }
  __syncthreads();

  const int lrow = tid >> 3;
  const int swq = (((tid & 7) * 16) ^ ((lrow & 7) << 4)) >> 1;
  const u16 *srcA[4], *srcB[4];
  #pragma unroll
  for (int it = 0; it < 4; ++it) {
    int r = it * 32 + lrow;
    int rr = (r < rows) ? r : 0;
    srcA[it] = hbuf + (size_t)(abase + rr) * EDIM + swq;
    srcB[it] = W2T + (size_t)(e * DM + n0 + r) * EDIM + swq;
  }

  const int w = tid >> 6, l = tid & 63;
  const int wm = (w >> 1) * 64, wn = (w & 1) * 64;
  const int lr = l & 15;
  const int lk = (l >> 4) * 16;

  f32x4 acc[4][4];
  #pragma unroll
  for (int i = 0; i < 4; ++i)
    #pragma unroll
    for (int j = 0; j < 4; ++j) acc[i][j] = (f32x4){0.f, 0.f, 0.f, 0.f};

  for (int kc = 0; kc < 3; ++kc) {
    const int ko = kc * 64;
    #pragma unroll
    for (int it = 0; it < 4; ++it) {
      gld16(srcA[it] + ko, (char*)As + (it * 256 + tid) * 16);
      gld16(srcB[it] + ko, (char*)Bs + (it * 256 + tid) * 16);
    }
    __syncthreads();
    #pragma unroll
    for (int kk = 0; kk < 2; ++kk) {
      const int kb = kk * 64 + lk;
      bf16x8 af[4], bf_[4];
      #pragma unroll
      for (int mf = 0; mf < 4; ++mf) af[mf] = frag_ld(As, wm + mf * 16 + lr, kb);
      #pragma unroll
      for (int nf = 0; nf < 4; ++nf) bf_[nf] = frag_ld(Bs, wn + nf * 16 + lr, kb);
      #pragma unroll
      for (int mf = 0; mf < 4; ++mf)
        #pragma unroll
        for (int nf = 0; nf < 4; ++nf)
          acc[mf][nf] = __builtin_amdgcn_mfma_f32_16x16x32_bf16(af[mf], bf_[nf], acc[mf][nf], 0, 0, 0);
    }
    __syncthreads();
  }

  const int rq = (l >> 4) * 4;
  #pragma unroll
  for (int mf = 0; mf < 4; ++mf)
    #pragma unroll
    for (int nf = 0; nf < 4; ++nf)
      #pragma unroll
      for (int r = 0; r < 4; ++r) {
        int m = wm + mf * 16 + rq + r;
        if (m < rows) {
          float v = acc[mf][nf][r] * gL[m];
          ypart[(size_t)dstL[m] + (n0 + wn + nf * 16 + lr)] = f2bf(v);
        }
      }
}

// ---------------------------------------------------------------------------
// Fused LN: 16 tokens x full 768 channels per block (2048 blocks).
// Exact stats (full row in-block); quad-cacheline NCHW write.
// ---------------------------------------------------------------------------
__global__ __launch_bounds__(256) void k_lnapply(
    const u16* __restrict__ ypart, const u16* __restrict__ tokbf,
    const float* __restrict__ gamma, const float* __restrict__ beta,
    float* __restrict__ out)
{
  __shared__ u16 yL[16][776];
  __shared__ u16 tkL[16][776];
  __shared__ float muL[16], rsL[16];
  const int tid = threadIdx.x;
  const int t0 = blockIdx.x * 16;
  const int b = t0 >> 10;
  const int h = (t0 >> 5) & 31;
  const int w0 = t0 & 31;           // 0 or 16

  {
    const int tl = tid >> 4, j = tid & 15;
    const u16* y0 = ypart + (size_t)(t0 + tl) * DM;
    const u16* y1 = y0 + (size_t)T_TOK * DM;
    const u16* tk = tokbf + (size_t)(t0 + tl) * DM;
    float sum = 0.f, sq = 0.f;
    #pragma unroll
    for (int i = 0; i < 6; ++i) {
      int c = i * 128 + j * 8;
      u16x8 a = *(const u16x8*)(y0 + c);
      u16x8 d = *(const u16x8*)(y1 + c);
      u16x8 t = *(const u16x8*)(tk + c);
      u16x8 o;
      #pragma unroll
      for (int q = 0; q < 8; ++q) {
        float v = bf2f(a[q]) + bf2f(d[q]);
        sum += v; sq += v * v;
        o[q] = f2bf(v);
      }
      *(u16x8*)&yL[tl][c] = o;
      *(u16x8*)&tkL[tl][c] = t;
    }
    #pragma unroll
    for (int d = 1; d < 16; d <<= 1) { sum += __shfl_xor(sum, d); sq += __shfl_xor(sq, d); }
    if (j == 0) {
      float m = sum * (1.f / 768.f);
      float var = sq * (1.f / 768.f) - m * m;
      muL[tl] = m;
      rsL[tl] = 1.f / sqrtf(var + 1e-5f);
    }
  }
  __syncthreads();

  {
    const int q = tid & 3, cq = tid >> 2;   // q: w-quad, cq: channel 0..63
    #pragma unroll
    for (int ci = 0; ci < 12; ++ci) {
      const int c = ci * 64 + cq;
      const float gc = gamma[c], bc = beta[c];
      const size_t oidx = (((size_t)b * DM + c) * 32 + h) * 32 + w0 + q * 4;
      float4 ov;
      #pragma unroll
      for (int i = 0; i < 4; ++i) {
        const int lt = q * 4 + i;
        float v = (bf2f(yL[lt][c]) - muL[lt]) * rsL[lt] * gc + bc + bf2f(tkL[lt][c]);
        (&ov.x)[i] = v;
      }
      *(float4*)(out + oidx) = ov;
    }
  }
}

// ---------------------------------------------------------------------------
// Workspace layout (all 256-aligned)
// ---------------------------------------------------------------------------
constexpr size_t OFF_TOK  = 0;
constexpr size_t OFF_W1T  = OFF_TOK + (size_t)T_TOK * DM * 2;
constexpr size_t OFF_W3T  = OFF_W1T + (size_t)NEXP * EDIM * DM * 2;
constexpr size_t OFF_W2T  = OFF_W3T + (size_t)NEXP * EDIM * DM * 2;
constexpr size_t OFF_H    = OFF_W2T + (size_t)NEXP * EDIM * DM * 2;
constexpr size_t OFF_YP   = OFF_H + (size_t)T_TOK * 2 * EDIM * 2;
constexpr size_t OFF_CNT  = OFF_YP + (size_t)2 * T_TOK * DM * 2;
constexpr size_t OFF_LIST = OFF_CNT + 256;
constexpr size_t OFF_GATE = OFF_LIST + (size_t)NEXP * T_TOK * 4;

extern "C" void kernel_launch(void* const* d_in, const int* in_sizes, int n_in,
                              void* d_out, int out_size, void* d_ws, size_t ws_size,
                              hipStream_t stream) {
  const float* x     = (const float*)d_in[0];
  const float* Wr    = (const float*)d_in[1];
  const float* W1    = (const float*)d_in[2];
  const float* W3    = (const float*)d_in[3];
  const float* W2    = (const float*)d_in[4];
  const float* gamma = (const float*)d_in[5];
  const float* beta  = (const float*)d_in[6];
  float* out = (float*)d_out;
  char* ws = (char*)d_ws;

  u16* tokbf = (u16*)(ws + OFF_TOK);
  u16* W1T   = (u16*)(ws + OFF_W1T);
  u16* W3T   = (u16*)(ws + OFF_W3T);
  u16* W2T   = (u16*)(ws + OFF_W2T);
  u16* hbuf  = (u16*)(ws + OFF_H);
  u16* ypart = (u16*)(ws + OFF_YP);
  int* cnt   = (int*)(ws + OFF_CNT);
  int* toklist = (int*)(ws + OFF_LIST);
  float* gatelist = (float*)(ws + OFF_GATE);

  hipMemsetAsync(cnt, 0, 64, stream);
  hipLaunchKernelGGL(k_tokprep, dim3(1888), dim3(256), 0, stream,
                     x, Wr, W1, W3, W2, tokbf, cnt, toklist, gatelist,
                     W1T, W3T, W2T);
  hipLaunchKernelGGL(k_ffn1, dim3(256, 3, 8), dim3(256), 0, stream,
                     tokbf, W1T, W3T, cnt, toklist, hbuf);
  hipLaunchKernelGGL(k_ffn2, dim3(256, 6, 8), dim3(256), 0, stream,
                     hbuf, W2T, cnt, toklist, gatelist, ypart);
  hipLaunchKernelGGL(k_lnapply, dim3(2048), dim3(256), 0, stream,
                     ypart, tokbf, gamma, beta, out);
}

// Round 13
// 215.037 us; speedup vs baseline: 1.0754x; 1.0754x over previous
//
#include <hip/hip_runtime.h>
#include <cstdint>
#include <cstddef>

#define T_TOK 32768
#define DM 768
#define EDIM 192
#define NEXP 8

typedef unsigned short u16;
typedef short bf16x8 __attribute__((ext_vector_type(8)));
typedef float f32x4 __attribute__((ext_vector_type(4)));
typedef u16 u16x8 __attribute__((ext_vector_type(8)));

__device__ __forceinline__ u16 f2bf(float f) {
  unsigned u = __float_as_uint(f);
  return (u16)((u + 0x7FFFu + ((u >> 16) & 1u)) >> 16);  // RNE
}
__device__ __forceinline__ float bf2f(u16 u) {
  return __uint_as_float(((unsigned)u) << 16);
}

// async global->LDS, 16B per lane. LDS dest must be wave-uniform base + lane*16.
__device__ __forceinline__ void gld16(const void* g, void* l) {
  __builtin_amdgcn_global_load_lds(
      (const __attribute__((address_space(1))) unsigned int*)g,
      (__attribute__((address_space(3))) unsigned int*)l,
      16, 0, 0);
}

// Read one MFMA fragment (8 bf16) from a swizzled LDS tile with 128-byte rows.
// Swizzle: phys_byte = row*128 + (kb ^ ((row&7)<<4))
__device__ __forceinline__ bf16x8 frag_ld(const u16* lds, int row, int kb) {
  int ph = row * 128 + (kb ^ ((row & 7) << 4));
  return *(const bf16x8*)((const char*)lds + ph);
}

// ---------------------------------------------------------------------------
// Fused: tokenize+router (blocks 0..1023) and weight transpose (blocks
// 1024..1887). Independent tasks overlapped in one dispatch.
// ---------------------------------------------------------------------------
__global__ __launch_bounds__(256) void k_tokprep(
    const float* __restrict__ x, const float* __restrict__ Wr,
    const float* __restrict__ W1, const float* __restrict__ W3,
    const float* __restrict__ W2,
    u16* __restrict__ tokbf, int* __restrict__ cnt,
    int* __restrict__ toklist, float* __restrict__ gatelist,
    u16* __restrict__ W1T, u16* __restrict__ W3T, u16* __restrict__ W2T)
{
  __shared__ __align__(16) char smraw[34304];
  const int tid = threadIdx.x;
  const int bx = blockIdx.x;

  if (bx >= 1024) {
    // ---- prep path: transpose + fp32->bf16 ----
    float (*td)[68] = (float(*)[68])smraw;   // [64][68]
    const int pid = bx - 1024;               // 0..863
    const int mat = pid / 288;
    const int rem = pid - mat * 288;
    const int e = rem / 36;
    const int tile = rem - e * 36;
    int R, C, r0, c0;
    if (mat < 2) { R = DM; C = EDIM; r0 = (tile / 3) * 64; c0 = (tile % 3) * 64; }
    else         { R = EDIM; C = DM; r0 = (tile / 12) * 64; c0 = (tile % 12) * 64; }
    const float* in = (mat == 0 ? W1 : mat == 1 ? W3 : W2) + (size_t)e * R * C;
    u16* out = (mat == 0 ? W1T : mat == 1 ? W3T : W2T) + (size_t)e * R * C;
    {
      int rl = tid >> 2, cs = (tid & 3) * 16;
      const float* s = in + (size_t)(r0 + rl) * C + c0 + cs;
      #pragma unroll
      for (int i = 0; i < 16; i += 4) *(float4*)&td[rl][cs + i] = *(const float4*)(s + i);
    }
    __syncthreads();
    {
      int cl = tid >> 2, rs = (tid & 3) * 16;
      u16* d = out + (size_t)(c0 + cl) * R + r0 + rs;
      u16x8 o0, o1;
      #pragma unroll
      for (int i = 0; i < 8; ++i) {
        o0[i] = f2bf(td[rs + i][cl]);
        o1[i] = f2bf(td[rs + 8 + i][cl]);
      }
      *(u16x8*)d = o0;
      *(u16x8*)(d + 8) = o1;
    }
    return;
  }

  // ---- router path ----
  float (*WrL)[772]    = (float(*)[772])smraw;                 // 24704 B
  float (*xL)[33]      = (float(*)[33])(smraw + 24704);        //  8448 B
  float (*logitsL)[8]  = (float(*)[8])(smraw + 33152);         //  1024 B
  int* cnt8            = (int*)(smraw + 34176);                //    32 B
  int* baseL           = (int*)(smraw + 34208);                //    32 B

  const int t0 = bx * 32;
  const int b = t0 >> 10;
  const int h = (t0 >> 5) & 31;
  const float* xb = x + (size_t)b * (DM * 1024) + h * 32;

  for (int i = tid; i < 1536; i += 256) {
    int r = i / 192;
    int c = (i - r * 192) * 4;
    *(float4*)&WrL[r][c] = ((const float4*)Wr)[i];
  }

  const int rt = tid >> 3;
  const int re = tid & 7;
  float lacc = 0.f;

  for (int cb = 0; cb < 12; ++cb) {
    const int c0 = cb * 64;
    __syncthreads();
    #pragma unroll
    for (int it = 0; it < 2; ++it) {
      int idx = it * 256 + tid;
      int r = idx >> 3, cc = (idx & 7) * 4;
      float4 v = *(const float4*)(xb + (size_t)(c0 + r) * 1024 + cc);
      xL[r][cc] = v.x; xL[r][cc + 1] = v.y; xL[r][cc + 2] = v.z; xL[r][cc + 3] = v.w;
    }
    __syncthreads();
    {
      const float* wr = &WrL[re][c0];
      #pragma unroll
      for (int c = 0; c < 64; ++c) lacc = fmaf(xL[c][rt], wr[c], lacc);
    }
    {
      u16x8 o;
      #pragma unroll
      for (int i = 0; i < 8; ++i) o[i] = f2bf(xL[re * 8 + i][rt]);
      *(u16x8*)(tokbf + (size_t)(t0 + rt) * DM + c0 + re * 8) = o;
    }
  }

  logitsL[rt][re] = lacc;
  if (tid < 8) cnt8[tid] = 0;
  __syncthreads();

  int e0 = -1, e1 = -1, lp0 = 0, lp1 = 0;
  float g0 = 0.f, g1 = 0.f;
  if (tid < 32) {
    float v0 = -1e30f, v1 = -1e30f;
    #pragma unroll
    for (int e = 0; e < 8; ++e) { float v = logitsL[tid][e]; if (v > v0) { v0 = v; e0 = e; } }
    #pragma unroll
    for (int e = 0; e < 8; ++e) {
      if (e == e0) continue;
      float v = logitsL[tid][e]; if (v > v1) { v1 = v; e1 = e; }
    }
    float w = expf(v1 - v0);
    g0 = 1.f / (1.f + w);
    g1 = w / (1.f + w);
    lp0 = atomicAdd(&cnt8[e0], 1);
    lp1 = atomicAdd(&cnt8[e1], 1);
  }
  __syncthreads();
  if (tid < 8) baseL[tid] = atomicAdd(&cnt[tid], cnt8[tid]);
  __syncthreads();
  if (tid < 32) {
    int tg = t0 + tid;
    int p0 = baseL[e0] + lp0;
    int p1 = baseL[e1] + lp1;
    toklist[e0 * T_TOK + p0] = tg;
    gatelist[e0 * T_TOK + p0] = g0;
    toklist[e1 * T_TOK + p1] = tg | (1 << 16);
    gatelist[e1 * T_TOK + p1] = g1;
  }
}

// ---------------------------------------------------------------------------
// Stage 1: h = silu(tok @ W1) * (tok @ W3). Tile 128x64, BK=64, 4 waves,
// single-buffered 33KB (proven optimum: 4 blocks/CU inter-block TLP beats
// every intra-block pipeline variant tried — R3/R5/R12). Grid (256, 3, 8).
// ---------------------------------------------------------------------------
__global__ __launch_bounds__(256) void k_ffn1(
    const u16* __restrict__ tokbf, const u16* __restrict__ W1T,
    const u16* __restrict__ W3T, const int* __restrict__ cnt,
    const int* __restrict__ toklist, u16* __restrict__ hbuf)
{
  __shared__ __align__(16) u16 As[128 * 64];
  __shared__ __align__(16) u16 B1s[64 * 64];
  __shared__ __align__(16) u16 B3s[64 * 64];
  __shared__ int rowbaseL[128];
  const int e = blockIdx.z;
  const int count = cnt[e];
  const int start = blockIdx.x * 128;
  if (start >= count) return;
  const int n0 = blockIdx.y * 64;
  const int rows = min(128, count - start);
  const int tid = threadIdx.x;

  int offe = 0;
  #pragma unroll
  for (int i = 0; i < NEXP; ++i) offe += (i < e) ? cnt[i] : 0;

  if (tid < 128) {
    int r = (tid < rows) ? tid : 0;
    rowbaseL[tid] = (toklist[e * T_TOK + start + r] & 0xFFFF) * DM;
  }
  __syncthreads();

  const int lrow = tid >> 3;                                   // 0..31
  const int swq = (((tid & 7) * 16) ^ ((lrow & 7) << 4)) >> 1; // u16 units
  const u16 *srcA[4], *srcB1[2], *srcB3[2];
  #pragma unroll
  for (int it = 0; it < 4; ++it)
    srcA[it] = tokbf + rowbaseL[it * 32 + lrow] + swq;
  #pragma unroll
  for (int it = 0; it < 2; ++it) {
    size_t wb = (size_t)(e * EDIM + n0 + it * 32 + lrow) * DM + swq;
    srcB1[it] = W1T + wb;
    srcB3[it] = W3T + wb;
  }

  const int w = tid >> 6, l = tid & 63;
  const int wm = (w >> 1) * 64, wn = (w & 1) * 32;
  const int lr = l & 15;
  const int lk = (l >> 4) * 16;

  f32x4 acc1[4][2], acc3[4][2];
  #pragma unroll
  for (int i = 0; i < 4; ++i)
    #pragma unroll
    for (int j = 0; j < 2; ++j) {
      acc1[i][j] = (f32x4){0.f, 0.f, 0.f, 0.f};
      acc3[i][j] = (f32x4){0.f, 0.f, 0.f, 0.f};
    }

  for (int kc = 0; kc < 12; ++kc) {
    const int ko = kc * 64;
    #pragma unroll
    for (int it = 0; it < 4; ++it)
      gld16(srcA[it] + ko, (char*)As + (it * 256 + tid) * 16);
    #pragma unroll
    for (int it = 0; it < 2; ++it) {
      gld16(srcB1[it] + ko, (char*)B1s + (it * 256 + tid) * 16);
      gld16(srcB3[it] + ko, (char*)B3s + (it * 256 + tid) * 16);
    }
    __syncthreads();
    #pragma unroll
    for (int kk = 0; kk < 2; ++kk) {
      const int kb = kk * 64 + lk;
      bf16x8 af[4], b1[2], b3[2];
      #pragma unroll
      for (int mf = 0; mf < 4; ++mf) af[mf] = frag_ld(As, wm + mf * 16 + lr, kb);
      #pragma unroll
      for (int nf = 0; nf < 2; ++nf) {
        b1[nf] = frag_ld(B1s, wn + nf * 16 + lr, kb);
        b3[nf] = frag_ld(B3s, wn + nf * 16 + lr, kb);
      }
      #pragma unroll
      for (int mf = 0; mf < 4; ++mf)
        #pragma unroll
        for (int nf = 0; nf < 2; ++nf) {
          acc1[mf][nf] = __builtin_amdgcn_mfma_f32_16x16x32_bf16(af[mf], b1[nf], acc1[mf][nf], 0, 0, 0);
          acc3[mf][nf] = __builtin_amdgcn_mfma_f32_16x16x32_bf16(af[mf], b3[nf], acc3[mf][nf], 0, 0, 0);
        }
    }
    __syncthreads();
  }

  const int rq = (l >> 4) * 4;
  const int abase = offe + start;
  #pragma unroll
  for (int mf = 0; mf < 4; ++mf)
    #pragma unroll
    for (int nf = 0; nf < 2; ++nf)
      #pragma unroll
      for (int r = 0; r < 4; ++r) {
        int m = wm + mf * 16 + rq + r;
        if (m < rows) {
          float a = acc1[mf][nf][r];
          float hv = (a / (1.f + expf(-a))) * acc3[mf][nf][r];
          hbuf[(size_t)(abase + m) * EDIM + (n0 + wn + nf * 16 + lr)] = f2bf(hv);
        }
      }
}

// ---------------------------------------------------------------------------
// Stage 2: ypart[k][t][:] = gate * (h @ W2[e]). Tile 128x128, K=192, 4 waves,
// single-buffered 33KB (R8-proven). Grid (256, 6, 8).
// ---------------------------------------------------------------------------
__global__ __launch_bounds__(256) void k_ffn2(
    const u16* __restrict__ hbuf, const u16* __restrict__ W2T,
    const int* __restrict__ cnt, const int* __restrict__ toklist,
    const float* __restrict__ gatelist, u16* __restrict__ ypart)
{
  __shared__ __align__(16) u16 As[128 * 64];
  __shared__ __align__(16) u16 Bs[128 * 64];
  __shared__ int dstL[128];
  __shared__ float gL[128];
  const int e = blockIdx.z;
  const int count = cnt[e];
  const int start = blockIdx.x * 128;
  if (start >= count) return;
  const int n0 = blockIdx.y * 128;
  const int rows = min(128, count - start);
  const int tid = threadIdx.x;

  int offe = 0;
  #pragma unroll
  for (int i = 0; i < NEXP; ++i) offe += (i < e) ? cnt[i] : 0;
  const int abase = offe + start;

  if (tid < 128) {
    int r = (tid < rows) ? tid : 0;
    int entry = toklist[e * T_TOK + start + r];
    int t = entry & 0xFFFF, k = entry >> 16;
    dstL[tid] = (k * T_TOK + t) * DM;
    gL[tid] = gatelist[e * T_TOK + start + r];
  }
  __syncthreads();

  const int lrow = tid >> 3;
  const int swq = (((tid & 7) * 16) ^ ((lrow & 7) << 4)) >> 1;
  const u16 *srcA[4], *srcB[4];
  #pragma unroll
  for (int it = 0; it < 4; ++it) {
    int r = it * 32 + lrow;
    int rr = (r < rows) ? r : 0;
    srcA[it] = hbuf + (size_t)(abase + rr) * EDIM + swq;
    srcB[it] = W2T + (size_t)(e * DM + n0 + r) * EDIM + swq;
  }

  const int w = tid >> 6, l = tid & 63;
  const int wm = (w >> 1) * 64, wn = (w & 1) * 64;
  const int lr = l & 15;
  const int lk = (l >> 4) * 16;

  f32x4 acc[4][4];
  #pragma unroll
  for (int i = 0; i < 4; ++i)
    #pragma unroll
    for (int j = 0; j < 4; ++j) acc[i][j] = (f32x4){0.f, 0.f, 0.f, 0.f};

  for (int kc = 0; kc < 3; ++kc) {
    const int ko = kc * 64;
    #pragma unroll
    for (int it = 0; it < 4; ++it) {
      gld16(srcA[it] + ko, (char*)As + (it * 256 + tid) * 16);
      gld16(srcB[it] + ko, (char*)Bs + (it * 256 + tid) * 16);
    }
    __syncthreads();
    #pragma unroll
    for (int kk = 0; kk < 2; ++kk) {
      const int kb = kk * 64 + lk;
      bf16x8 af[4], bf_[4];
      #pragma unroll
      for (int mf = 0; mf < 4; ++mf) af[mf] = frag_ld(As, wm + mf * 16 + lr, kb);
      #pragma unroll
      for (int nf = 0; nf < 4; ++nf) bf_[nf] = frag_ld(Bs, wn + nf * 16 + lr, kb);
      #pragma unroll
      for (int mf = 0; mf < 4; ++mf)
        #pragma unroll
        for (int nf = 0; nf < 4; ++nf)
          acc[mf][nf] = __builtin_amdgcn_mfma_f32_16x16x32_bf16(af[mf], bf_[nf], acc[mf][nf], 0, 0, 0);
    }
    __syncthreads();
  }

  const int rq = (l >> 4) * 4;
  #pragma unroll
  for (int mf = 0; mf < 4; ++mf)
    #pragma unroll
    for (int nf = 0; nf < 4; ++nf)
      #pragma unroll
      for (int r = 0; r < 4; ++r) {
        int m = wm + mf * 16 + rq + r;
        if (m < rows) {
          float v = acc[mf][nf][r] * gL[m];
          ypart[(size_t)dstL[m] + (n0 + wn + nf * 16 + lr)] = f2bf(v);
        }
      }
}

// ---------------------------------------------------------------------------
// Fused LN: 16 tokens x full 768 channels per block (2048 blocks).
// Exact stats (full row in-block); quad-cacheline NCHW write.
// ---------------------------------------------------------------------------
__global__ __launch_bounds__(256) void k_lnapply(
    const u16* __restrict__ ypart, const u16* __restrict__ tokbf,
    const float* __restrict__ gamma, const float* __restrict__ beta,
    float* __restrict__ out)
{
  __shared__ u16 yL[16][776];
  __shared__ u16 tkL[16][776];
  __shared__ float muL[16], rsL[16];
  const int tid = threadIdx.x;
  const int t0 = blockIdx.x * 16;
  const int b = t0 >> 10;
  const int h = (t0 >> 5) & 31;
  const int w0 = t0 & 31;           // 0 or 16

  {
    const int tl = tid >> 4, j = tid & 15;
    const u16* y0 = ypart + (size_t)(t0 + tl) * DM;
    const u16* y1 = y0 + (size_t)T_TOK * DM;
    const u16* tk = tokbf + (size_t)(t0 + tl) * DM;
    float sum = 0.f, sq = 0.f;
    #pragma unroll
    for (int i = 0; i < 6; ++i) {
      int c = i * 128 + j * 8;
      u16x8 a = *(const u16x8*)(y0 + c);
      u16x8 d = *(const u16x8*)(y1 + c);
      u16x8 t = *(const u16x8*)(tk + c);
      u16x8 o;
      #pragma unroll
      for (int q = 0; q < 8; ++q) {
        float v = bf2f(a[q]) + bf2f(d[q]);
        sum += v; sq += v * v;
        o[q] = f2bf(v);
      }
      *(u16x8*)&yL[tl][c] = o;
      *(u16x8*)&tkL[tl][c] = t;
    }
    #pragma unroll
    for (int d = 1; d < 16; d <<= 1) { sum += __shfl_xor(sum, d); sq += __shfl_xor(sq, d); }
    if (j == 0) {
      float m = sum * (1.f / 768.f);
      float var = sq * (1.f / 768.f) - m * m;
      muL[tl] = m;
      rsL[tl] = 1.f / sqrtf(var + 1e-5f);
    }
  }
  __syncthreads();

  {
    const int q = tid & 3, cq = tid >> 2;   // q: w-quad, cq: channel 0..63
    #pragma unroll
    for (int ci = 0; ci < 12; ++ci) {
      const int c = ci * 64 + cq;
      const float gc = gamma[c], bc = beta[c];
      const size_t oidx = (((size_t)b * DM + c) * 32 + h) * 32 + w0 + q * 4;
      float4 ov;
      #pragma unroll
      for (int i = 0; i < 4; ++i) {
        const int lt = q * 4 + i;
        float v = (bf2f(yL[lt][c]) - muL[lt]) * rsL[lt] * gc + bc + bf2f(tkL[lt][c]);
        (&ov.x)[i] = v;
      }
      *(float4*)(out + oidx) = ov;
    }
  }
}

// ---------------------------------------------------------------------------
// Workspace layout (all 256-aligned)
// ---------------------------------------------------------------------------
constexpr size_t OFF_TOK  = 0;
constexpr size_t OFF_W1T  = OFF_TOK + (size_t)T_TOK * DM * 2;
constexpr size_t OFF_W3T  = OFF_W1T + (size_t)NEXP * EDIM * DM * 2;
constexpr size_t OFF_W2T  = OFF_W3T + (size_t)NEXP * EDIM * DM * 2;
constexpr size_t OFF_H    = OFF_W2T + (size_t)NEXP * EDIM * DM * 2;
constexpr size_t OFF_YP   = OFF_H + (size_t)T_TOK * 2 * EDIM * 2;
constexpr size_t OFF_CNT  = OFF_YP + (size_t)2 * T_TOK * DM * 2;
constexpr size_t OFF_LIST = OFF_CNT + 256;
constexpr size_t OFF_GATE = OFF_LIST + (size_t)NEXP * T_TOK * 4;

extern "C" void kernel_launch(void* const* d_in, const int* in_sizes, int n_in,
                              void* d_out, int out_size, void* d_ws, size_t ws_size,
                              hipStream_t stream) {
  const float* x     = (const float*)d_in[0];
  const float* Wr    = (const float*)d_in[1];
  const float* W1    = (const float*)d_in[2];
  const float* W3    = (const float*)d_in[3];
  const float* W2    = (const float*)d_in[4];
  const float* gamma = (const float*)d_in[5];
  const float* beta  = (const float*)d_in[6];
  float* out = (float*)d_out;
  char* ws = (char*)d_ws;

  u16* tokbf = (u16*)(ws + OFF_TOK);
  u16* W1T   = (u16*)(ws + OFF_W1T);
  u16* W3T   = (u16*)(ws + OFF_W3T);
  u16* W2T   = (u16*)(ws + OFF_W2T);
  u16* hbuf  = (u16*)(ws + OFF_H);
  u16* ypart = (u16*)(ws + OFF_YP);
  int* cnt   = (int*)(ws + OFF_CNT);
  int* toklist = (int*)(ws + OFF_LIST);
  float* gatelist = (float*)(ws + OFF_GATE);

  hipMemsetAsync(cnt, 0, 64, stream);
  hipLaunchKernelGGL(k_tokprep, dim3(1888), dim3(256), 0, stream,
                     x, Wr, W1, W3, W2, tokbf, cnt, toklist, gatelist,
                     W1T, W3T, W2T);
  hipLaunchKernelGGL(k_ffn1, dim3(256, 3, 8), dim3(256), 0, stream,
                     tokbf, W1T, W3T, cnt, toklist, hbuf);
  hipLaunchKernelGGL(k_ffn2, dim3(256, 6, 8), dim3(256), 0, stream,
                     hbuf, W2T, cnt, toklist, gatelist, ypart);
  hipLaunchKernelGGL(k_lnapply, dim3(2048), dim3(256), 0, stream,
                     ypart, tokbf, gamma, beta, out);
}